// Round 6
// baseline (10967.534 us; speedup 1.0000x reference)
//
#include <hip/hip_runtime.h>
#include <cmath>

#define LOG2E 1.44269504088896340736f
#define TMAX 2048

#if __has_builtin(__builtin_amdgcn_exp2f)
#define EXP2F(x) __builtin_amdgcn_exp2f(x)
#else
#define EXP2F(x) exp2f(x)
#endif
#if __has_builtin(__builtin_amdgcn_rcpf)
#define RCPF(x) __builtin_amdgcn_rcpf(x)
#else
#define RCPF(x) (1.0f / (x))
#endif

typedef float float2v __attribute__((ext_vector_type(2)));
typedef float float4v __attribute__((ext_vector_type(4)));

__device__ __forceinline__ float fexp(float x)  { return EXP2F(x * LOG2E); }
// tanh(x) = 1 - 2/(1 + e^{2x})
__device__ __forceinline__ float ftanh(float x) { return 1.0f - 2.0f * RCPF(1.0f + EXP2F(x * (2.0f * LOG2E))); }
// _step(x) = (tanh(5x)+1)/2 = sigmoid(10x)
__device__ __forceinline__ float fstep(float x) { return RCPF(1.0f + EXP2F(x * (-10.0f * LOG2E))); }
__device__ __forceinline__ float fsinh(float x) { float e = fexp(x); return 0.5f * (e - RCPF(e)); }

__device__ __forceinline__ int fadd_i(int a, int b) {
    return __builtin_bit_cast(int, __builtin_bit_cast(float, a) + __builtin_bit_cast(float, b));
}

// full-wave (64 lane) sum via DPP tree; wave-uniform result (readlane 63).
__device__ __forceinline__ float wave_allsum(float x) {
    int v = __builtin_bit_cast(int, x);
    v = fadd_i(v, __builtin_amdgcn_update_dpp(0, v, 0x111, 0xF, 0xF, true)); // row_shr:1
    v = fadd_i(v, __builtin_amdgcn_update_dpp(0, v, 0x112, 0xF, 0xF, true)); // row_shr:2
    v = fadd_i(v, __builtin_amdgcn_update_dpp(0, v, 0x114, 0xF, 0xF, true)); // row_shr:4
    v = fadd_i(v, __builtin_amdgcn_update_dpp(0, v, 0x118, 0xF, 0xF, true)); // row_shr:8
    v = fadd_i(v, __builtin_amdgcn_update_dpp(0, v, 0x142, 0xA, 0xF, true)); // row_bcast:15
    v = fadd_i(v, __builtin_amdgcn_update_dpp(0, v, 0x143, 0xC, 0xF, true)); // row_bcast:31
    return __builtin_bit_cast(float, __builtin_amdgcn_readlane(v, 63));
}

// packed fp32 fma: d = a*b + c on both 32-bit halves (one VOP3P inst)
__device__ __forceinline__ float2v pk_fma(float2v a, float2v b, float2v c) {
    float2v d;
    asm("v_pk_fma_f32 %0, %1, %2, %3" : "=v"(d) : "v"(a), "v"(b), "v"(c));
    return d;
}

__global__ __launch_bounds__(64, 1)
void exphydro_kernel(const float* __restrict__ g_snow, const float* __restrict__ g_water,
                     const float* __restrict__ g_pr, const float* __restrict__ g_tm,
                     const float* __restrict__ g_ld, const float* __restrict__ g_t,
                     const float* __restrict__ W1, const float* __restrict__ b1,
                     const float* __restrict__ W2, const float* __restrict__ b2,
                     const float* __restrict__ W3, const float* __restrict__ b3,
                     const float* __restrict__ W4, const float* __restrict__ b4,
                     float* __restrict__ out, int T, int B)
{
    const int lane = threadIdx.x;
    const int bA = 2 * blockIdx.x;
    const int bB = (bA + 1 < B) ? bA + 1 : bA;   // clamp (duplicate work if B odd)

    // two samples' forcing, interleaved {pr, tm, ld, t} per timestep
    __shared__ __align__(16) float4v s_fA[TMAX];
    __shared__ __align__(16) float4v s_fB[TMAX];
    __shared__ __align__(16) float hbA[64];
    __shared__ __align__(16) float hbB[64];

    for (int i = lane; i < T; i += 64) {
        float tv = g_t[i];
        s_fA[i] = float4v{g_pr[bA * T + i], g_tm[bA * T + i], g_ld[bA * T + i], tv};
        s_fB[i] = float4v{g_pr[bB * T + i], g_tm[bB * T + i], g_ld[bB * T + i], tv};
    }

    // weights (shared across samples): lane i = column i of W1/W2/W3, row i of W4
    float w1r[4], w4r[5], b4r[5];
    float2v w2p[32], w3p[32];
#pragma unroll
    for (int j = 0; j < 4; ++j) w1r[j] = W1[j * 64 + lane];
    float b1v = b1[lane];
#pragma unroll
    for (int k = 0; k < 32; ++k) {
        w2p[k] = float2v{W2[(2 * k) * 64 + lane], W2[(2 * k + 1) * 64 + lane]};
        w3p[k] = float2v{W3[(2 * k) * 64 + lane], W3[(2 * k + 1) * 64 + lane]};
    }
    float b2v = b2[lane];
    float b3v = b3[lane];
#pragma unroll
    for (int k = 0; k < 5; ++k) { w4r[k] = W4[lane * 5 + k]; b4r[k] = b4[k]; }

    __syncthreads();

    // dual 64x64 matvec: two independent samples share every weight register;
    // A/B instruction streams interleave to fill each other's latency bubbles.
    // LDS broadcast per sample (single wave: DS pipe in-order, no barrier).
    auto matvec2 = [&](const float2v (&w)[32], float xA, float xB, float bias,
                       float& yA, float& yB) {
        hbA[lane] = xA;
        hbB[lane] = xB;
        float2v aA0 = float2v{bias, 0.0f}, aA1 = float2v{0.0f, 0.0f},
                aA2 = float2v{0.0f, 0.0f}, aA3 = float2v{0.0f, 0.0f};
        float2v aB0 = float2v{bias, 0.0f}, aB1 = float2v{0.0f, 0.0f},
                aB2 = float2v{0.0f, 0.0f}, aB3 = float2v{0.0f, 0.0f};
#pragma unroll
        for (int j = 0; j < 64; j += 8) {
            float4v hA0 = *reinterpret_cast<const float4v*>(&hbA[j]);
            float4v hA1 = *reinterpret_cast<const float4v*>(&hbA[j + 4]);
            float4v hB0 = *reinterpret_cast<const float4v*>(&hbB[j]);
            float4v hB1 = *reinterpret_cast<const float4v*>(&hbB[j + 4]);
            aA0 = pk_fma(w[j / 2 + 0], __builtin_shufflevector(hA0, hA0, 0, 1), aA0);
            aB0 = pk_fma(w[j / 2 + 0], __builtin_shufflevector(hB0, hB0, 0, 1), aB0);
            aA1 = pk_fma(w[j / 2 + 1], __builtin_shufflevector(hA0, hA0, 2, 3), aA1);
            aB1 = pk_fma(w[j / 2 + 1], __builtin_shufflevector(hB0, hB0, 2, 3), aB1);
            aA2 = pk_fma(w[j / 2 + 2], __builtin_shufflevector(hA1, hA1, 0, 1), aA2);
            aB2 = pk_fma(w[j / 2 + 2], __builtin_shufflevector(hB1, hB1, 0, 1), aB2);
            aA3 = pk_fma(w[j / 2 + 3], __builtin_shufflevector(hA1, hA1, 2, 3), aA3);
            aB3 = pk_fma(w[j / 2 + 3], __builtin_shufflevector(hB1, hB1, 2, 3), aB3);
        }
        float2v sA = (aA0 + aA1) + (aA2 + aA3);
        float2v sB = (aB0 + aB1) + (aB2 + aB3);
        yA = sA.x + sA.y;
        yB = sB.x + sB.y;
    };

    // dual MLP: wave-uniform inputs per sample -> wave-uniform o[5] per sample
    auto mlp2 = [&](float x0A, float x1A, float x2A, float x3A,
                    float x0B, float x1B, float x2B, float x3B,
                    float* oA, float* oB) {
        float h1A = ftanh(fmaf(w1r[3], x3A, fmaf(w1r[2], x2A, fmaf(w1r[1], x1A, fmaf(w1r[0], x0A, b1v)))));
        float h1B = ftanh(fmaf(w1r[3], x3B, fmaf(w1r[2], x2B, fmaf(w1r[1], x1B, fmaf(w1r[0], x0B, b1v)))));
        float h2A, h2B, h3A, h3B;
        matvec2(w2p, h1A, h1B, b2v, h2A, h2B);
        h2A = ftanh(h2A); h2B = ftanh(h2B);
        matvec2(w3p, h2A, h2B, b3v, h3A, h3B);
        h3A = ftanh(h3A); h3B = ftanh(h3B);
#pragma unroll
        for (int k = 0; k < 5; ++k) {
            oA[k] = wave_allsum(w4r[k] * h3A) + b4r[k];
            oB[k] = wave_allsum(w4r[k] * h3B) + b4r[k];
        }
    };

    // dual rhs: everything wave-uniform; epilogues interleave across samples
    auto rhs2 = [&](float y0A, float y1A, float prA, float tmA, float ldA, float snA,
                    float y0B, float y1B, float prB, float tmB, float ldB, float snB,
                    float& d0A, float& d1A, float& o4A,
                    float& d0B, float& d1B, float& o4B) {
        float oA[5], oB[5];
        mlp2(y0A, y1A, prA, tmA, y0B, y1B, prB, tmB, oA, oB);
        float psA = fmaxf(0.0f, fsinh(oA[0]) * snA);
        float psB = fmaxf(0.0f, fsinh(oB[0]) * snB);
        float prnA = fmaxf(0.0f, fsinh(oA[1]));
        float prnB = fmaxf(0.0f, fsinh(oB[1]));
        float mA = fmaxf(0.0f, fstep(y0A) * fsinh(oA[2]));
        float mB = fmaxf(0.0f, fstep(y0B) * fsinh(oB[2]));
        float s1A = fstep(y1A), s1B = fstep(y1B);
        float eqA = s1A * fmaf(fexp(oA[3]), ldA, fexp(oA[4]));
        float eqB = s1B * fmaf(fexp(oB[3]), ldB, fexp(oB[4]));
        d0A = psA - mA;            d0B = psB - mB;
        d1A = (prnA + mA) - eqA;   d1B = (prnB + mB) - eqB;
        o4A = oA[4];               o4B = oB[4];
    };

    float y0A = g_snow[bA * T], y1A = g_water[bA * T];
    float y0B = g_snow[bB * T], y1B = g_water[bB * T];

    for (int st = 0; st < T - 1; ++st) {
        float4v fcA = s_fA[st], fnA = s_fA[st + 1];
        float4v fcB = s_fB[st], fnB = s_fB[st + 1];

        float dt = fnA.w - fcA.w, half = 0.5f * dt, c6 = dt * (1.0f / 6.0f);
        float prHA = 0.5f * (fcA.x + fnA.x), tmHA = 0.5f * (fcA.y + fnA.y), ldHA = 0.5f * (fcA.z + fnA.z);
        float prHB = 0.5f * (fcB.x + fnB.x), tmHB = 0.5f * (fcB.y + fnB.y), ldHB = 0.5f * (fcB.z + fnB.z);
        // forcing-only nonlinearities off the serial chain
        float snAA = fstep(-fcA.y), snHA = fstep(-tmHA), snCA = fstep(-fnA.y);
        float snAB = fstep(-fcB.y), snHB = fstep(-tmHB), snCB = fstep(-fnB.y);

        float k1aA, k1bA, k2aA, k2bA, k3aA, k3bA, k4aA, k4bA, o4A, o4xA;
        float k1aB, k1bB, k2aB, k2bB, k3aB, k3bB, k4aB, k4bB, o4B, o4xB;

        rhs2(y0A, y1A, fcA.x, fcA.y, fcA.z, snAA,
             y0B, y1B, fcB.x, fcB.y, fcB.z, snAB,
             k1aA, k1bA, o4A, k1aB, k1bB, o4B);
        // q_out[:, st] == o[4] of the k1 MLP eval (integer-time interp == raw series)
        if (lane == 0) { out[bA * T + st] = o4A; out[bB * T + st] = o4B; }

        rhs2(fmaf(half, k1aA, y0A), fmaf(half, k1bA, y1A), prHA, tmHA, ldHA, snHA,
             fmaf(half, k1aB, y0B), fmaf(half, k1bB, y1B), prHB, tmHB, ldHB, snHB,
             k2aA, k2bA, o4xA, k2aB, k2bB, o4xB);

        rhs2(fmaf(half, k2aA, y0A), fmaf(half, k2bA, y1A), prHA, tmHA, ldHA, snHA,
             fmaf(half, k2aB, y0B), fmaf(half, k2bB, y1B), prHB, tmHB, ldHB, snHB,
             k3aA, k3bA, o4xA, k3aB, k3bB, o4xB);

        rhs2(fmaf(dt, k3aA, y0A), fmaf(dt, k3bA, y1A), fnA.x, fnA.y, fnA.z, snCA,
             fmaf(dt, k3aB, y0B), fmaf(dt, k3bB, y1B), fnB.x, fnB.y, fnB.z, snCB,
             k4aA, k4bA, o4xA, k4aB, k4bB, o4xB);

        y0A = fmaf(c6, (k1aA + k4aA) + 2.0f * (k2aA + k3aA), y0A);
        y1A = fmaf(c6, (k1bA + k4bA) + 2.0f * (k2bA + k3bA), y1A);
        y0B = fmaf(c6, (k1aB + k4aB) + 2.0f * (k2aB + k3aB), y0B);
        y1B = fmaf(c6, (k1bB + k4bB) + 2.0f * (k2bB + k3bB), y1B);
    }

    // last readout at t = T-1 with raw series values and final state
    {
        float4v fLA = s_fA[T - 1], fLB = s_fB[T - 1];
        float oA[5], oB[5];
        mlp2(y0A, y1A, fLA.x, fLA.y, y0B, y1B, fLB.x, fLB.y, oA, oB);
        if (lane == 0) { out[bA * T + (T - 1)] = oA[4]; out[bB * T + (T - 1)] = oB[4]; }
    }
}

extern "C" void kernel_launch(void* const* d_in, const int* in_sizes, int n_in,
                              void* d_out, int out_size, void* d_ws, size_t ws_size,
                              hipStream_t stream) {
    const float* g_snow  = (const float*)d_in[0];
    const float* g_water = (const float*)d_in[1];
    const float* g_pr    = (const float*)d_in[2];
    const float* g_tm    = (const float*)d_in[3];
    const float* g_ld    = (const float*)d_in[4];
    const float* g_t     = (const float*)d_in[5];
    const float* W1 = (const float*)d_in[6];
    const float* b1 = (const float*)d_in[7];
    const float* W2 = (const float*)d_in[8];
    const float* b2 = (const float*)d_in[9];
    const float* W3 = (const float*)d_in[10];
    const float* b3 = (const float*)d_in[11];
    const float* W4 = (const float*)d_in[12];
    const float* b4 = (const float*)d_in[13];

    const int T = in_sizes[5];
    const int B = in_sizes[0] / T;
    const int nblk = (B + 1) / 2;

    exphydro_kernel<<<dim3(nblk), dim3(64), 0, stream>>>(
        g_snow, g_water, g_pr, g_tm, g_ld, g_t,
        W1, b1, W2, b2, W3, b3, W4, b4,
        (float*)d_out, T, B);
}

// Round 7
// 5920.721 us; speedup vs baseline: 1.8524x; 1.8524x over previous
//
#include <hip/hip_runtime.h>
#include <cmath>

#define LOG2E 1.44269504088896340736f
#define TMAX 2048

#if __has_builtin(__builtin_amdgcn_exp2f)
#define EXP2F(x) __builtin_amdgcn_exp2f(x)
#else
#define EXP2F(x) exp2f(x)
#endif
#if __has_builtin(__builtin_amdgcn_rcpf)
#define RCPF(x) __builtin_amdgcn_rcpf(x)
#else
#define RCPF(x) (1.0f / (x))
#endif

typedef float float2v __attribute__((ext_vector_type(2)));
typedef float float4v __attribute__((ext_vector_type(4)));

__device__ __forceinline__ float fexp(float x)  { return EXP2F(x * LOG2E); }
// tanh(x) = 1 - 2/(1 + e^{2x})
__device__ __forceinline__ float ftanh(float x) { return 1.0f - 2.0f * RCPF(1.0f + EXP2F(x * (2.0f * LOG2E))); }
// _step(x) = (tanh(5x)+1)/2 = sigmoid(10x)
__device__ __forceinline__ float fstep(float x) { return RCPF(1.0f + EXP2F(x * (-10.0f * LOG2E))); }
__device__ __forceinline__ float fsinh(float x) { float e = fexp(x); return 0.5f * (e - RCPF(e)); }

__device__ __forceinline__ int fadd_i(int a, int b) {
    return __builtin_bit_cast(int, __builtin_bit_cast(float, a) + __builtin_bit_cast(float, b));
}

// full-wave (64 lane) sum via DPP tree; TOTAL VALID IN LANE 63 ONLY.
__device__ __forceinline__ float wave_sum63(float x) {
    int v = __builtin_bit_cast(int, x);
    v = fadd_i(v, __builtin_amdgcn_update_dpp(0, v, 0x111, 0xF, 0xF, true)); // row_shr:1
    v = fadd_i(v, __builtin_amdgcn_update_dpp(0, v, 0x112, 0xF, 0xF, true)); // row_shr:2
    v = fadd_i(v, __builtin_amdgcn_update_dpp(0, v, 0x114, 0xF, 0xF, true)); // row_shr:4
    v = fadd_i(v, __builtin_amdgcn_update_dpp(0, v, 0x118, 0xF, 0xF, true)); // row_shr:8
    v = fadd_i(v, __builtin_amdgcn_update_dpp(0, v, 0x142, 0xA, 0xF, true)); // row_bcast:15
    v = fadd_i(v, __builtin_amdgcn_update_dpp(0, v, 0x143, 0xC, 0xF, true)); // row_bcast:31
    return __builtin_bit_cast(float, v);
}

// packed fp32 fma: d = a*b + c on both 32-bit halves (one VOP3P inst)
__device__ __forceinline__ float2v pk_fma(float2v a, float2v b, float2v c) {
    float2v d;
    asm("v_pk_fma_f32 %0, %1, %2, %3" : "=v"(d) : "v"(a), "v"(b), "v"(c));
    return d;
}

__device__ __forceinline__ float2v vlo(float4v v) { return __builtin_shufflevector(v, v, 0, 1); }
__device__ __forceinline__ float2v vhi(float4v v) { return __builtin_shufflevector(v, v, 2, 3); }

__global__ __launch_bounds__(256, 1)
void exphydro_kernel(const float* __restrict__ g_snow, const float* __restrict__ g_water,
                     const float* __restrict__ g_pr, const float* __restrict__ g_tm,
                     const float* __restrict__ g_ld, const float* __restrict__ g_t,
                     const float* __restrict__ W1, const float* __restrict__ b1,
                     const float* __restrict__ W2, const float* __restrict__ b2,
                     const float* __restrict__ W3, const float* __restrict__ b3,
                     const float* __restrict__ W4, const float* __restrict__ b4,
                     float* __restrict__ out, int T)
{
    const int tid  = threadIdx.x;
    const int lane = tid & 63;
    const int wid  = tid >> 6;     // wave id 0..3, one SIMD each
    const int b    = blockIdx.x;   // one sample per block

    // forcing interleaved {pr, tm, ld, t} per timestep -- broadcast b128 reads
    __shared__ __align__(16) float4v s_f[TMAX];
    // per-wave private h broadcast copies (own-copy => within-wave DS order, no barrier)
    __shared__ __align__(16) float hcopy[4][64];
    // cross-wave partial buffers, double-buffered across layers (race-free)
    __shared__ __align__(16) float partA[64][4];
    __shared__ __align__(16) float partB[64][4];
    __shared__ __align__(16) float obuf[8];

    for (int i = tid; i < T; i += 256) {
        s_f[i] = float4v{g_pr[b * T + i], g_tm[b * T + i], g_ld[b * T + i], g_t[i]};
    }

    // layer-1 weights (all waves), K-slice of W2/W3 (rows [16*wid, 16*wid+16)),
    // W4 tree weights distributed across waves (wave3 takes trees 3 and 4)
    float w1r[4];
#pragma unroll
    for (int j = 0; j < 4; ++j) w1r[j] = W1[j * 64 + lane];
    float b1v = b1[lane];

    float2v w2s[8], w3s[8];
#pragma unroll
    for (int k = 0; k < 8; ++k) {
        int r = 16 * wid + 2 * k;
        w2s[k] = float2v{W2[r * 64 + lane], W2[(r + 1) * 64 + lane]};
        w3s[k] = float2v{W3[r * 64 + lane], W3[(r + 1) * 64 + lane]};
    }
    float b2v = (wid == 0) ? b2[lane] : 0.0f;
    float b3v = (wid == 0) ? b3[lane] : 0.0f;
    float w4a = W4[lane * 5 + wid];
    float w4b = (wid == 3) ? W4[lane * 5 + 4] : 0.0f;
    float b4a = b4[wid];
    float b4b = b4[4];

    __syncthreads();

    // K-split quarter matvec: 4 broadcast b128 reads of own h-copy + 8 pk_fma
    auto quarter_dot = [&](const float* hq, const float2v (&w)[8], float bias) -> float {
        float4v q0 = *reinterpret_cast<const float4v*>(hq + 0);
        float4v q1 = *reinterpret_cast<const float4v*>(hq + 4);
        float4v q2 = *reinterpret_cast<const float4v*>(hq + 8);
        float4v q3 = *reinterpret_cast<const float4v*>(hq + 12);
        float2v a0 = float2v{bias, 0.0f}, a1 = float2v{0.0f, 0.0f};
        a0 = pk_fma(w[0], vlo(q0), a0); a1 = pk_fma(w[1], vhi(q0), a1);
        a0 = pk_fma(w[2], vlo(q1), a0); a1 = pk_fma(w[3], vhi(q1), a1);
        a0 = pk_fma(w[4], vlo(q2), a0); a1 = pk_fma(w[5], vhi(q2), a1);
        a0 = pk_fma(w[6], vlo(q3), a0); a1 = pk_fma(w[7], vhi(q3), a1);
        float2v s = a0 + a1;
        return s.x + s.y;
    };

    // full MLP from per-lane h1; fills obuf[0..4]; ends after a barrier
    auto mlp_obuf = [&](float h1) {
        float* hown = &hcopy[wid][0];
        const float* hq = hown + 16 * wid;
        // layer 2
        hown[lane] = h1;
        partA[lane][wid] = quarter_dot(hq, w2s, b2v);
        __syncthreads();
        float4v p2 = *reinterpret_cast<const float4v*>(&partA[lane][0]);
        float h2 = ftanh((p2.x + p2.y) + (p2.z + p2.w));
        // layer 3
        hown[lane] = h2;
        partB[lane][wid] = quarter_dot(hq, w3s, b3v);
        __syncthreads();
        float4v p3 = *reinterpret_cast<const float4v*>(&partB[lane][0]);
        float h3 = ftanh((p3.x + p3.y) + (p3.z + p3.w));
        // layer 4: distributed DPP trees
        float t1 = wave_sum63(w4a * h3);
        if (wid == 3) {
            float t2 = wave_sum63(w4b * h3);
            if (lane == 63) { obuf[3] = t1 + b4a; obuf[4] = t2 + b4b; }
        } else {
            if (lane == 63) obuf[wid] = t1 + b4a;
        }
        __syncthreads();
    };

    // rhs: base = b1 + W1[2]*pr + W1[3]*tm (per-lane, precomputed per interp pt)
    auto rhs = [&](float base, float y0v, float y1v, float ld, float snt,
                   float& d0, float& d1, float& o4) {
        float h1 = ftanh(fmaf(w1r[0], y0v, fmaf(w1r[1], y1v, base)));
        mlp_obuf(h1);
        float4v ov = *reinterpret_cast<const float4v*>(&obuf[0]);
        float o4v = obuf[4];
        float psnow = fmaxf(0.0f, fsinh(ov.x) * snt);
        float prain = fmaxf(0.0f, fsinh(ov.y));
        float melt  = fmaxf(0.0f, fstep(y0v) * fsinh(ov.z));
        float eq    = fstep(y1v) * fmaf(fexp(ov.w), ld, fexp(o4v));
        d0 = psnow - melt;
        d1 = (prain + melt) - eq;
        o4 = o4v;
    };

    // wave-uniform state, replicated per wave (identical arithmetic => identical)
    float y0v = g_snow[b * T];
    float y1v = g_water[b * T];

    for (int st = 0; st < T - 1; ++st) {
        float4v fc = s_f[st];
        float4v fn = s_f[st + 1];

        float dt = fn.w - fc.w, half = 0.5f * dt, c6 = dt * (1.0f / 6.0f);
        float prH = 0.5f * (fc.x + fn.x);
        float tmH = 0.5f * (fc.y + fn.y);
        float ldH = 0.5f * (fc.z + fn.z);
        float snA = fstep(-fc.y), snH = fstep(-tmH), snC = fstep(-fn.y);
        float baseA = fmaf(w1r[2], fc.x, fmaf(w1r[3], fc.y, b1v));
        float baseH = fmaf(w1r[2], prH,  fmaf(w1r[3], tmH,  b1v));
        float baseC = fmaf(w1r[2], fn.x, fmaf(w1r[3], fn.y, b1v));

        float k1a, k1b, k2a, k2b, k3a, k3b, k4a, k4b, o4a, o4x;
        rhs(baseA, y0v, y1v, fc.z, snA, k1a, k1b, o4a);
        // q_out[:, st] == o[4] of the k1 MLP eval (integer-time interp == raw series)
        if (tid == 0) out[b * T + st] = o4a;
        rhs(baseH, fmaf(half, k1a, y0v), fmaf(half, k1b, y1v), ldH, snH, k2a, k2b, o4x);
        rhs(baseH, fmaf(half, k2a, y0v), fmaf(half, k2b, y1v), ldH, snH, k3a, k3b, o4x);
        rhs(baseC, fmaf(dt, k3a, y0v),   fmaf(dt, k3b, y1v),   fn.z, snC, k4a, k4b, o4x);

        y0v = fmaf(c6, (k1a + k4a) + 2.0f * (k2a + k3a), y0v);
        y1v = fmaf(c6, (k1b + k4b) + 2.0f * (k2b + k3b), y1v);
    }

    // last readout at t = T-1 with raw series values and final state
    {
        float4v fL = s_f[T - 1];
        float base = fmaf(w1r[2], fL.x, fmaf(w1r[3], fL.y, b1v));
        float h1 = ftanh(fmaf(w1r[0], y0v, fmaf(w1r[1], y1v, base)));
        mlp_obuf(h1);
        if (tid == 0) out[b * T + (T - 1)] = obuf[4];
    }
}

extern "C" void kernel_launch(void* const* d_in, const int* in_sizes, int n_in,
                              void* d_out, int out_size, void* d_ws, size_t ws_size,
                              hipStream_t stream) {
    const float* g_snow  = (const float*)d_in[0];
    const float* g_water = (const float*)d_in[1];
    const float* g_pr    = (const float*)d_in[2];
    const float* g_tm    = (const float*)d_in[3];
    const float* g_ld    = (const float*)d_in[4];
    const float* g_t     = (const float*)d_in[5];
    const float* W1 = (const float*)d_in[6];
    const float* b1 = (const float*)d_in[7];
    const float* W2 = (const float*)d_in[8];
    const float* b2 = (const float*)d_in[9];
    const float* W3 = (const float*)d_in[10];
    const float* b3 = (const float*)d_in[11];
    const float* W4 = (const float*)d_in[12];
    const float* b4 = (const float*)d_in[13];

    const int T = in_sizes[5];
    const int B = in_sizes[0] / T;

    exphydro_kernel<<<dim3(B), dim3(256), 0, stream>>>(
        g_snow, g_water, g_pr, g_tm, g_ld, g_t,
        W1, b1, W2, b2, W3, b3, W4, b4,
        (float*)d_out, T);
}

// Round 8
// 5844.654 us; speedup vs baseline: 1.8765x; 1.0130x over previous
//
#include <hip/hip_runtime.h>
#include <cmath>

#define LOG2E 1.44269504088896340736f
#define TMAX 2048

#if __has_builtin(__builtin_amdgcn_exp2f)
#define EXP2F(x) __builtin_amdgcn_exp2f(x)
#else
#define EXP2F(x) exp2f(x)
#endif
#if __has_builtin(__builtin_amdgcn_rcpf)
#define RCPF(x) __builtin_amdgcn_rcpf(x)
#else
#define RCPF(x) (1.0f / (x))
#endif

typedef float float2v __attribute__((ext_vector_type(2)));
typedef float float4v __attribute__((ext_vector_type(4)));

__device__ __forceinline__ float fexp(float x)  { return EXP2F(x * LOG2E); }
// tanh(x) = 1 - 2/(1 + e^{2x})
__device__ __forceinline__ float ftanh(float x) { return 1.0f - 2.0f * RCPF(1.0f + EXP2F(x * (2.0f * LOG2E))); }
// _step(x) = (tanh(5x)+1)/2 = sigmoid(10x)
__device__ __forceinline__ float fstep(float x) { return RCPF(1.0f + EXP2F(x * (-10.0f * LOG2E))); }
__device__ __forceinline__ float fsinh(float x) { float e = fexp(x); return 0.5f * (e - RCPF(e)); }

__device__ __forceinline__ int fadd_i(int a, int b) {
    return __builtin_bit_cast(int, __builtin_bit_cast(float, a) + __builtin_bit_cast(float, b));
}

// full-wave (64 lane) sum via DPP tree; TOTAL VALID IN LANE 63 ONLY.
__device__ __forceinline__ float wave_sum63(float x) {
    int v = __builtin_bit_cast(int, x);
    v = fadd_i(v, __builtin_amdgcn_update_dpp(0, v, 0x111, 0xF, 0xF, true)); // row_shr:1
    v = fadd_i(v, __builtin_amdgcn_update_dpp(0, v, 0x112, 0xF, 0xF, true)); // row_shr:2
    v = fadd_i(v, __builtin_amdgcn_update_dpp(0, v, 0x114, 0xF, 0xF, true)); // row_shr:4
    v = fadd_i(v, __builtin_amdgcn_update_dpp(0, v, 0x118, 0xF, 0xF, true)); // row_shr:8
    v = fadd_i(v, __builtin_amdgcn_update_dpp(0, v, 0x142, 0xA, 0xF, true)); // row_bcast:15
    v = fadd_i(v, __builtin_amdgcn_update_dpp(0, v, 0x143, 0xC, 0xF, true)); // row_bcast:31
    return __builtin_bit_cast(float, v);
}

// broadcast lane l's value to all lanes (lands in SGPR)
__device__ __forceinline__ float rl(float x, int l) {
    return __builtin_bit_cast(float, __builtin_amdgcn_readlane(__builtin_bit_cast(int, x), l));
}

// packed fp32 fma: d = a*b + c on both 32-bit halves (one VOP3P inst)
__device__ __forceinline__ float2v pk_fma(float2v a, float2v b, float2v c) {
    float2v d;
    asm("v_pk_fma_f32 %0, %1, %2, %3" : "=v"(d) : "v"(a), "v"(b), "v"(c));
    return d;
}

__device__ __forceinline__ float2v vlo(float4v v) { return __builtin_shufflevector(v, v, 0, 1); }
__device__ __forceinline__ float2v vhi(float4v v) { return __builtin_shufflevector(v, v, 2, 3); }

__global__ __launch_bounds__(256, 1)
void exphydro_kernel(const float* __restrict__ g_snow, const float* __restrict__ g_water,
                     const float* __restrict__ g_pr, const float* __restrict__ g_tm,
                     const float* __restrict__ g_ld, const float* __restrict__ g_t,
                     const float* __restrict__ W1, const float* __restrict__ b1,
                     const float* __restrict__ W2, const float* __restrict__ b2,
                     const float* __restrict__ W3, const float* __restrict__ b3,
                     const float* __restrict__ W4, const float* __restrict__ b4,
                     float* __restrict__ out, int T)
{
    const int tid  = threadIdx.x;
    const int lane = tid & 63;
    const int wid  = tid >> 6;     // wave id 0..3, one SIMD each
    const int b    = blockIdx.x;   // one sample per block

    // forcing interleaved {pr, tm, ld, t} per timestep -- broadcast b128 reads
    __shared__ __align__(16) float4v s_f[TMAX];
    // per-wave private h broadcast copies (own-copy => within-wave DS order, no barrier)
    __shared__ __align__(16) float hcopy[4][64];
    // cross-wave partial buffers, w-major: write part[wid][lane] is stride-1
    // across lanes (conflict-free); read part[w][lane] w=0..3 is 4 conflict-free
    // b32 reads (pairable into ds_read2_b32). Double-buffered across layers.
    __shared__ __align__(16) float partA[4][64];
    __shared__ __align__(16) float partB[4][64];

    for (int i = tid; i < T; i += 256) {
        s_f[i] = float4v{g_pr[b * T + i], g_tm[b * T + i], g_ld[b * T + i], g_t[i]};
    }

    // layer-1 weights (all waves), K-slice of W2/W3 (rows [16*wid, 16*wid+16)),
    // full W4 per lane (trees computed redundantly in every wave -- no exchange)
    float w1r[4];
#pragma unroll
    for (int j = 0; j < 4; ++j) w1r[j] = W1[j * 64 + lane];
    float b1v = b1[lane];

    float2v w2s[8], w3s[8];
#pragma unroll
    for (int k = 0; k < 8; ++k) {
        int r = 16 * wid + 2 * k;
        w2s[k] = float2v{W2[r * 64 + lane], W2[(r + 1) * 64 + lane]};
        w3s[k] = float2v{W3[r * 64 + lane], W3[(r + 1) * 64 + lane]};
    }
    float b2v = (wid == 0) ? b2[lane] : 0.0f;
    float b3v = (wid == 0) ? b3[lane] : 0.0f;
    float w4r[5], b4r[5];
#pragma unroll
    for (int k = 0; k < 5; ++k) { w4r[k] = W4[lane * 5 + k]; b4r[k] = b4[k]; }

    __syncthreads();

    // K-split quarter matvec: 4 broadcast b128 reads of own h-copy + 8 pk_fma
    auto quarter_dot = [&](const float* hq, const float2v (&w)[8], float bias) -> float {
        float4v q0 = *reinterpret_cast<const float4v*>(hq + 0);
        float4v q1 = *reinterpret_cast<const float4v*>(hq + 4);
        float4v q2 = *reinterpret_cast<const float4v*>(hq + 8);
        float4v q3 = *reinterpret_cast<const float4v*>(hq + 12);
        float2v a0 = float2v{bias, 0.0f}, a1 = float2v{0.0f, 0.0f};
        a0 = pk_fma(w[0], vlo(q0), a0); a1 = pk_fma(w[1], vhi(q0), a1);
        a0 = pk_fma(w[2], vlo(q1), a0); a1 = pk_fma(w[3], vhi(q1), a1);
        a0 = pk_fma(w[4], vlo(q2), a0); a1 = pk_fma(w[5], vhi(q2), a1);
        a0 = pk_fma(w[6], vlo(q3), a0); a1 = pk_fma(w[7], vhi(q3), a1);
        float2v s = a0 + a1;
        return s.x + s.y;
    };

    // full MLP from per-lane h1; o[0..4] VALID IN LANE 63 of every wave.
    // 2 barriers total (part exchanges); layer-4 trees redundant per wave.
    auto mlp_o63 = [&](float h1, float* o) {
        float* hown = &hcopy[wid][0];
        const float* hq = hown + 16 * wid;
        // layer 2
        hown[lane] = h1;
        partA[wid][lane] = quarter_dot(hq, w2s, b2v);
        __syncthreads();
        float h2 = ftanh((partA[0][lane] + partA[1][lane]) + (partA[2][lane] + partA[3][lane]));
        // layer 3
        hown[lane] = h2;
        partB[wid][lane] = quarter_dot(hq, w3s, b3v);
        __syncthreads();
        float h3 = ftanh((partB[0][lane] + partB[1][lane]) + (partB[2][lane] + partB[3][lane]));
        // layer 4: 5 DPP trees, redundant in every wave (no LDS, no barrier)
#pragma unroll
        for (int k = 0; k < 5; ++k) o[k] = wave_sum63(w4r[k] * h3) + b4r[k];
    };

    // rhs: d0,d1 wave-uniform via readlane(63); o4 valid in lane 63 only.
    auto rhs = [&](float base, float y0v, float y1v, float ld, float snt,
                   float& d0, float& d1, float& o4) {
        float h1 = ftanh(fmaf(w1r[0], y0v, fmaf(w1r[1], y1v, base)));
        float o[5];
        mlp_o63(h1, o);
        // epilogue computed with lane-63 values (garbage in other lanes, unused)
        float psnow = fmaxf(0.0f, fsinh(o[0]) * snt);
        float prain = fmaxf(0.0f, fsinh(o[1]));
        float melt  = fmaxf(0.0f, fstep(y0v) * fsinh(o[2]));
        float eq    = fstep(y1v) * fmaf(fexp(o[3]), ld, fexp(o[4]));
        float d0l = psnow - melt;
        float d1l = (prain + melt) - eq;
        d0 = rl(d0l, 63);
        d1 = rl(d1l, 63);
        o4 = o[4];
    };

    // wave-uniform state, replicated per wave (identical arithmetic => identical)
    float y0v = g_snow[b * T];
    float y1v = g_water[b * T];

    for (int st = 0; st < T - 1; ++st) {
        float4v fc = s_f[st];
        float4v fn = s_f[st + 1];

        float dt = fn.w - fc.w, half = 0.5f * dt, c6 = dt * (1.0f / 6.0f);
        float prH = 0.5f * (fc.x + fn.x);
        float tmH = 0.5f * (fc.y + fn.y);
        float ldH = 0.5f * (fc.z + fn.z);
        float snA = fstep(-fc.y), snH = fstep(-tmH), snC = fstep(-fn.y);
        float baseA = fmaf(w1r[2], fc.x, fmaf(w1r[3], fc.y, b1v));
        float baseH = fmaf(w1r[2], prH,  fmaf(w1r[3], tmH,  b1v));
        float baseC = fmaf(w1r[2], fn.x, fmaf(w1r[3], fn.y, b1v));

        float k1a, k1b, k2a, k2b, k3a, k3b, k4a, k4b, o4a, o4x;
        rhs(baseA, y0v, y1v, fc.z, snA, k1a, k1b, o4a);
        // q_out[:, st] == o[4] of the k1 MLP eval (integer-time interp == raw series)
        if (tid == 63) out[b * T + st] = o4a;
        rhs(baseH, fmaf(half, k1a, y0v), fmaf(half, k1b, y1v), ldH, snH, k2a, k2b, o4x);
        rhs(baseH, fmaf(half, k2a, y0v), fmaf(half, k2b, y1v), ldH, snH, k3a, k3b, o4x);
        rhs(baseC, fmaf(dt, k3a, y0v),   fmaf(dt, k3b, y1v),   fn.z, snC, k4a, k4b, o4x);

        y0v = fmaf(c6, (k1a + k4a) + 2.0f * (k2a + k3a), y0v);
        y1v = fmaf(c6, (k1b + k4b) + 2.0f * (k2b + k3b), y1v);
    }

    // last readout at t = T-1 with raw series values and final state
    {
        float4v fL = s_f[T - 1];
        float base = fmaf(w1r[2], fL.x, fmaf(w1r[3], fL.y, b1v));
        float h1 = ftanh(fmaf(w1r[0], y0v, fmaf(w1r[1], y1v, base)));
        float o[5];
        mlp_o63(h1, o);
        if (tid == 63) out[b * T + (T - 1)] = o[4];
    }
}

extern "C" void kernel_launch(void* const* d_in, const int* in_sizes, int n_in,
                              void* d_out, int out_size, void* d_ws, size_t ws_size,
                              hipStream_t stream) {
    const float* g_snow  = (const float*)d_in[0];
    const float* g_water = (const float*)d_in[1];
    const float* g_pr    = (const float*)d_in[2];
    const float* g_tm    = (const float*)d_in[3];
    const float* g_ld    = (const float*)d_in[4];
    const float* g_t     = (const float*)d_in[5];
    const float* W1 = (const float*)d_in[6];
    const float* b1 = (const float*)d_in[7];
    const float* W2 = (const float*)d_in[8];
    const float* b2 = (const float*)d_in[9];
    const float* W3 = (const float*)d_in[10];
    const float* b3 = (const float*)d_in[11];
    const float* W4 = (const float*)d_in[12];
    const float* b4 = (const float*)d_in[13];

    const int T = in_sizes[5];
    const int B = in_sizes[0] / T;

    exphydro_kernel<<<dim3(B), dim3(256), 0, stream>>>(
        g_snow, g_water, g_pr, g_tm, g_ld, g_t,
        W1, b1, W2, b2, W3, b3, W4, b4,
        (float*)d_out, T);
}

// Round 9
// 5143.222 us; speedup vs baseline: 2.1324x; 1.1364x over previous
//
#include <hip/hip_runtime.h>
#include <cmath>

#define LOG2E 1.44269504088896340736f
#define TMAX 2048

#if __has_builtin(__builtin_amdgcn_exp2f)
#define EXP2F(x) __builtin_amdgcn_exp2f(x)
#else
#define EXP2F(x) exp2f(x)
#endif
#if __has_builtin(__builtin_amdgcn_rcpf)
#define RCPF(x) __builtin_amdgcn_rcpf(x)
#else
#define RCPF(x) (1.0f / (x))
#endif

typedef float float2v __attribute__((ext_vector_type(2)));
typedef float float4v __attribute__((ext_vector_type(4)));

__device__ __forceinline__ float fexp(float x)  { return EXP2F(x * LOG2E); }
// tanh(x) = 1 - 2/(1 + e^{2x})
__device__ __forceinline__ float ftanh(float x) { return 1.0f - 2.0f * RCPF(1.0f + EXP2F(x * (2.0f * LOG2E))); }
// _step(x) = (tanh(5x)+1)/2 = sigmoid(10x)
__device__ __forceinline__ float fstep(float x) { return RCPF(1.0f + EXP2F(x * (-10.0f * LOG2E))); }
__device__ __forceinline__ float fsinh(float x) { float e = fexp(x); return 0.5f * (e - RCPF(e)); }

__device__ __forceinline__ int fadd_i(int a, int b) {
    return __builtin_bit_cast(int, __builtin_bit_cast(float, a) + __builtin_bit_cast(float, b));
}

// full-wave (64 lane) sum via DPP tree; TOTAL VALID IN LANE 63 ONLY.
__device__ __forceinline__ float wave_sum63(float x) {
    int v = __builtin_bit_cast(int, x);
    v = fadd_i(v, __builtin_amdgcn_update_dpp(0, v, 0x111, 0xF, 0xF, true)); // row_shr:1
    v = fadd_i(v, __builtin_amdgcn_update_dpp(0, v, 0x112, 0xF, 0xF, true)); // row_shr:2
    v = fadd_i(v, __builtin_amdgcn_update_dpp(0, v, 0x114, 0xF, 0xF, true)); // row_shr:4
    v = fadd_i(v, __builtin_amdgcn_update_dpp(0, v, 0x118, 0xF, 0xF, true)); // row_shr:8
    v = fadd_i(v, __builtin_amdgcn_update_dpp(0, v, 0x142, 0xA, 0xF, true)); // row_bcast:15
    v = fadd_i(v, __builtin_amdgcn_update_dpp(0, v, 0x143, 0xC, 0xF, true)); // row_bcast:31
    return __builtin_bit_cast(float, v);
}

// quad (4-lane) all-sum via 2 DPP quad_perm adds (valid in all 4 lanes)
__device__ __forceinline__ float quad_sum(float x) {
    int v = __builtin_bit_cast(int, x);
    v = fadd_i(v, __builtin_amdgcn_update_dpp(0, v, 0xB1, 0xF, 0xF, true)); // quad_perm [1,0,3,2]
    v = fadd_i(v, __builtin_amdgcn_update_dpp(0, v, 0x4E, 0xF, 0xF, true)); // quad_perm [2,3,0,1]
    return __builtin_bit_cast(float, v);
}

// broadcast lane l's value to all lanes (lands in SGPR)
__device__ __forceinline__ float rl(float x, int l) {
    return __builtin_bit_cast(float, __builtin_amdgcn_readlane(__builtin_bit_cast(int, x), l));
}

// packed fp32 fma: d = a*b + c on both 32-bit halves (one VOP3P inst)
__device__ __forceinline__ float2v pk_fma(float2v a, float2v b, float2v c) {
    float2v d;
    asm("v_pk_fma_f32 %0, %1, %2, %3" : "=v"(d) : "v"(a), "v"(b), "v"(c));
    return d;
}

__device__ __forceinline__ float2v vlo(float4v v) { return __builtin_shufflevector(v, v, 0, 1); }
__device__ __forceinline__ float2v vhi(float4v v) { return __builtin_shufflevector(v, v, 2, 3); }

__global__ __launch_bounds__(256, 1)
void exphydro_kernel(const float* __restrict__ g_snow, const float* __restrict__ g_water,
                     const float* __restrict__ g_pr, const float* __restrict__ g_tm,
                     const float* __restrict__ g_ld, const float* __restrict__ g_t,
                     const float* __restrict__ W1, const float* __restrict__ b1,
                     const float* __restrict__ W2, const float* __restrict__ b2,
                     const float* __restrict__ W3, const float* __restrict__ b3,
                     const float* __restrict__ W4, const float* __restrict__ b4,
                     float* __restrict__ out, int T)
{
    const int tid  = threadIdx.x;
    const int lane = tid & 63;
    const int wid  = tid >> 6;     // wave id 0..3, one SIMD each
    const int b    = blockIdx.x;   // one sample per block
    const int qk   = lane & 3;     // L2: K-subslice (rows [qk*16, qk*16+16))
    const int qo   = lane >> 2;    // L2: output index within this wave's slice
    const int col2 = 16 * wid + qo; // L2 output column this lane computes

    // forcing interleaved {pr, tm, ld, t} per timestep -- broadcast b128 reads
    __shared__ __align__(16) float4v s_f[TMAX];
    // per-wave private full h1 copy (in-wave DS order => no barrier)
    __shared__ __align__(16) float hc[4][64];
    // per-wave h2 slice (computed AND consumed by the same wave)
    __shared__ __align__(16) float hs[4][16];
    // L3 partial exchange, double-buffered across consecutive rhs calls
    __shared__ __align__(16) float partAB[2][4][64];

    for (int i = tid; i < T; i += 256) {
        s_f[i] = float4v{g_pr[b * T + i], g_tm[b * T + i], g_ld[b * T + i], g_t[i]};
    }

    // --- weights ---
    // layer 1: all waves identical (per-lane column)
    float w1r[4];
#pragma unroll
    for (int j = 0; j < 4; ++j) w1r[j] = W1[j * 64 + lane];
    float b1v = b1[lane];
    // layer 2, N-split: lane computes output col2 over K-rows [qk*16, qk*16+16)
    float2v w2n[8];
#pragma unroll
    for (int k = 0; k < 8; ++k) {
        int r = qk * 16 + 2 * k;
        w2n[k] = float2v{W2[r * 64 + col2], W2[(r + 1) * 64 + col2]};
    }
    float b2s = b2[col2];
    // layer 3, K-split: wave owns rows [16*wid, 16*wid+16), lane = output col
    float2v w3s[8];
#pragma unroll
    for (int k = 0; k < 8; ++k) {
        int r = 16 * wid + 2 * k;
        w3s[k] = float2v{W3[r * 64 + lane], W3[(r + 1) * 64 + lane]};
    }
    float b3v = (wid == 0) ? b3[lane] : 0.0f;
    // layer 4: full, redundant per wave
    float w4r[5], b4r[5];
#pragma unroll
    for (int k = 0; k < 5; ++k) { w4r[k] = W4[lane * 5 + k]; b4r[k] = b4[k]; }

    __syncthreads();

    // full MLP from per-lane h1; o[0..4] VALID IN LANE 63 of every wave.
    // ONE barrier per call (L3 partial exchange).
    auto mlp_o63 = [&](float h1, float (*part)[64], float* o) {
        // self-broadcast h1 within wave (h1 is identical in all waves)
        hc[wid][lane] = h1;
        const float* hq = &hc[wid][qk * 16];
        float4v q0 = *reinterpret_cast<const float4v*>(hq + 0);
        float4v q1 = *reinterpret_cast<const float4v*>(hq + 4);
        float4v q2 = *reinterpret_cast<const float4v*>(hq + 8);
        float4v q3 = *reinterpret_cast<const float4v*>(hq + 12);
        // L2 partial: 16-deep over this lane's K-subslice, output col2
        float2v a0 = float2v{0.0f, 0.0f}, a1 = float2v{0.0f, 0.0f};
        a0 = pk_fma(w2n[0], vlo(q0), a0); a1 = pk_fma(w2n[1], vhi(q0), a1);
        a0 = pk_fma(w2n[2], vlo(q1), a0); a1 = pk_fma(w2n[3], vhi(q1), a1);
        a0 = pk_fma(w2n[4], vlo(q2), a0); a1 = pk_fma(w2n[5], vhi(q2), a1);
        a0 = pk_fma(w2n[6], vlo(q3), a0); a1 = pk_fma(w2n[7], vhi(q3), a1);
        float2v sa = a0 + a1;
        float t2 = quad_sum(sa.x + sa.y);           // full 64-deep dot in quad
        float h2 = ftanh(t2 + b2s);
        // publish this wave's h2 slice (consumed only by the SAME wave)
        if (qk == 0) hs[wid][qo] = h2;
        float4v r0 = *reinterpret_cast<const float4v*>(&hs[wid][0]);
        float4v r1 = *reinterpret_cast<const float4v*>(&hs[wid][4]);
        float4v r2 = *reinterpret_cast<const float4v*>(&hs[wid][8]);
        float4v r3 = *reinterpret_cast<const float4v*>(&hs[wid][12]);
        // L3 K-split partial for output `lane`
        float2v c0 = float2v{b3v, 0.0f}, c1 = float2v{0.0f, 0.0f};
        c0 = pk_fma(w3s[0], vlo(r0), c0); c1 = pk_fma(w3s[1], vhi(r0), c1);
        c0 = pk_fma(w3s[2], vlo(r1), c0); c1 = pk_fma(w3s[3], vhi(r1), c1);
        c0 = pk_fma(w3s[4], vlo(r2), c0); c1 = pk_fma(w3s[5], vhi(r2), c1);
        c0 = pk_fma(w3s[6], vlo(r3), c0); c1 = pk_fma(w3s[7], vhi(r3), c1);
        float2v sc = c0 + c1;
        part[wid][lane] = sc.x + sc.y;
        __syncthreads();                             // the ONE barrier
        float h3 = ftanh((part[0][lane] + part[1][lane]) + (part[2][lane] + part[3][lane]));
        // L4: 5 DPP trees, redundant in every wave (no LDS, no barrier)
#pragma unroll
        for (int k = 0; k < 5; ++k) o[k] = wave_sum63(w4r[k] * h3) + b4r[k];
    };

    // rhs: d0,d1 wave-uniform via readlane(63); o4 valid in lane 63 only.
    auto rhs = [&](float base, float y0v, float y1v, float ld, float snt,
                   float (*part)[64], float& d0, float& d1, float& o4) {
        float h1 = ftanh(fmaf(w1r[0], y0v, fmaf(w1r[1], y1v, base)));
        float o[5];
        mlp_o63(h1, part, o);
        // epilogue computed with lane-63 values (garbage in other lanes, unused)
        float psnow = fmaxf(0.0f, fsinh(o[0]) * snt);
        float prain = fmaxf(0.0f, fsinh(o[1]));
        float melt  = fmaxf(0.0f, fstep(y0v) * fsinh(o[2]));
        float eq    = fstep(y1v) * fmaf(fexp(o[3]), ld, fexp(o[4]));
        float d0l = psnow - melt;
        float d1l = (prain + melt) - eq;
        d0 = rl(d0l, 63);
        d1 = rl(d1l, 63);
        o4 = o[4];
    };

    // wave-uniform state, replicated per wave (identical arithmetic => identical)
    float y0v = g_snow[b * T];
    float y1v = g_water[b * T];

    for (int st = 0; st < T - 1; ++st) {
        float4v fc = s_f[st];
        float4v fn = s_f[st + 1];

        float dt = fn.w - fc.w, half = 0.5f * dt, c6 = dt * (1.0f / 6.0f);
        float prH = 0.5f * (fc.x + fn.x);
        float tmH = 0.5f * (fc.y + fn.y);
        float ldH = 0.5f * (fc.z + fn.z);
        float snA = fstep(-fc.y), snH = fstep(-tmH), snC = fstep(-fn.y);
        float baseA = fmaf(w1r[2], fc.x, fmaf(w1r[3], fc.y, b1v));
        float baseH = fmaf(w1r[2], prH,  fmaf(w1r[3], tmH,  b1v));
        float baseC = fmaf(w1r[2], fn.x, fmaf(w1r[3], fn.y, b1v));

        float k1a, k1b, k2a, k2b, k3a, k3b, k4a, k4b, o4a, o4x;
        rhs(baseA, y0v, y1v, fc.z, snA, partAB[0], k1a, k1b, o4a);
        // q_out[:, st] == o[4] of the k1 MLP eval (integer-time interp == raw series)
        if (tid == 63) out[b * T + st] = o4a;
        rhs(baseH, fmaf(half, k1a, y0v), fmaf(half, k1b, y1v), ldH, snH, partAB[1], k2a, k2b, o4x);
        rhs(baseH, fmaf(half, k2a, y0v), fmaf(half, k2b, y1v), ldH, snH, partAB[0], k3a, k3b, o4x);
        rhs(baseC, fmaf(dt, k3a, y0v),   fmaf(dt, k3b, y1v),   fn.z, snC, partAB[1], k4a, k4b, o4x);

        y0v = fmaf(c6, (k1a + k4a) + 2.0f * (k2a + k3a), y0v);
        y1v = fmaf(c6, (k1b + k4b) + 2.0f * (k2b + k3b), y1v);
    }

    // last readout at t = T-1 with raw series values and final state
    {
        float4v fL = s_f[T - 1];
        float base = fmaf(w1r[2], fL.x, fmaf(w1r[3], fL.y, b1v));
        float h1 = ftanh(fmaf(w1r[0], y0v, fmaf(w1r[1], y1v, base)));
        float o[5];
        mlp_o63(h1, partAB[0], o);
        if (tid == 63) out[b * T + (T - 1)] = o[4];
    }
}

extern "C" void kernel_launch(void* const* d_in, const int* in_sizes, int n_in,
                              void* d_out, int out_size, void* d_ws, size_t ws_size,
                              hipStream_t stream) {
    const float* g_snow  = (const float*)d_in[0];
    const float* g_water = (const float*)d_in[1];
    const float* g_pr    = (const float*)d_in[2];
    const float* g_tm    = (const float*)d_in[3];
    const float* g_ld    = (const float*)d_in[4];
    const float* g_t     = (const float*)d_in[5];
    const float* W1 = (const float*)d_in[6];
    const float* b1 = (const float*)d_in[7];
    const float* W2 = (const float*)d_in[8];
    const float* b2 = (const float*)d_in[9];
    const float* W3 = (const float*)d_in[10];
    const float* b3 = (const float*)d_in[11];
    const float* W4 = (const float*)d_in[12];
    const float* b4 = (const float*)d_in[13];

    const int T = in_sizes[5];
    const int B = in_sizes[0] / T;

    exphydro_kernel<<<dim3(B), dim3(256), 0, stream>>>(
        g_snow, g_water, g_pr, g_tm, g_ld, g_t,
        W1, b1, W2, b2, W3, b3, W4, b4,
        (float*)d_out, T);
}

// Round 10
// 4807.552 us; speedup vs baseline: 2.2813x; 1.0698x over previous
//
#include <hip/hip_runtime.h>
#include <cmath>

#define LOG2E 1.44269504088896340736f
#define TMAX 2048

#if __has_builtin(__builtin_amdgcn_exp2f)
#define EXP2F(x) __builtin_amdgcn_exp2f(x)
#else
#define EXP2F(x) exp2f(x)
#endif
#if __has_builtin(__builtin_amdgcn_rcpf)
#define RCPF(x) __builtin_amdgcn_rcpf(x)
#else
#define RCPF(x) (1.0f / (x))
#endif

typedef float float2v __attribute__((ext_vector_type(2)));
typedef float float4v __attribute__((ext_vector_type(4)));

__device__ __forceinline__ float fexp(float x)  { return EXP2F(x * LOG2E); }
// tanh(x) = 1 - 2/(1 + e^{2x})
__device__ __forceinline__ float ftanh(float x) { return 1.0f - 2.0f * RCPF(1.0f + EXP2F(x * (2.0f * LOG2E))); }
// _step(x) = (tanh(5x)+1)/2 = sigmoid(10x)
__device__ __forceinline__ float fstep(float x) { return RCPF(1.0f + EXP2F(x * (-10.0f * LOG2E))); }
__device__ __forceinline__ float fsinh(float x) { float e = fexp(x); return 0.5f * (e - RCPF(e)); }

__device__ __forceinline__ int fadd_i(int a, int b) {
    return __builtin_bit_cast(int, __builtin_bit_cast(float, a) + __builtin_bit_cast(float, b));
}

// full-wave (64 lane) sum via DPP tree; TOTAL VALID IN LANE 63 ONLY.
__device__ __forceinline__ float wave_sum63(float x) {
    int v = __builtin_bit_cast(int, x);
    v = fadd_i(v, __builtin_amdgcn_update_dpp(0, v, 0x111, 0xF, 0xF, true)); // row_shr:1
    v = fadd_i(v, __builtin_amdgcn_update_dpp(0, v, 0x112, 0xF, 0xF, true)); // row_shr:2
    v = fadd_i(v, __builtin_amdgcn_update_dpp(0, v, 0x114, 0xF, 0xF, true)); // row_shr:4
    v = fadd_i(v, __builtin_amdgcn_update_dpp(0, v, 0x118, 0xF, 0xF, true)); // row_shr:8
    v = fadd_i(v, __builtin_amdgcn_update_dpp(0, v, 0x142, 0xA, 0xF, true)); // row_bcast:15
    v = fadd_i(v, __builtin_amdgcn_update_dpp(0, v, 0x143, 0xC, 0xF, true)); // row_bcast:31
    return __builtin_bit_cast(float, v);
}

// quad (4-lane) all-sum via 2 DPP quad_perm adds (valid in all 4 lanes)
__device__ __forceinline__ float quad_sum(float x) {
    int v = __builtin_bit_cast(int, x);
    v = fadd_i(v, __builtin_amdgcn_update_dpp(0, v, 0xB1, 0xF, 0xF, true)); // quad_perm [1,0,3,2]
    v = fadd_i(v, __builtin_amdgcn_update_dpp(0, v, 0x4E, 0xF, 0xF, true)); // quad_perm [2,3,0,1]
    return __builtin_bit_cast(float, v);
}

// broadcast lane l's value to all lanes (lands in SGPR)
__device__ __forceinline__ float rl(float x, int l) {
    return __builtin_bit_cast(float, __builtin_amdgcn_readlane(__builtin_bit_cast(int, x), l));
}

// packed fp32 fma: d = a*b + c on both 32-bit halves (one VOP3P inst)
__device__ __forceinline__ float2v pk_fma(float2v a, float2v b, float2v c) {
    float2v d;
    asm("v_pk_fma_f32 %0, %1, %2, %3" : "=v"(d) : "v"(a), "v"(b), "v"(c));
    return d;
}

__device__ __forceinline__ float2v vlo(float4v v) { return __builtin_shufflevector(v, v, 0, 1); }
__device__ __forceinline__ float2v vhi(float4v v) { return __builtin_shufflevector(v, v, 2, 3); }

// lgkmcnt-only barrier: ds_writes must be LDS-visible, but do NOT drain vmcnt
// (the per-step `out` global store would otherwise stall every wave here).
__device__ __forceinline__ void barrier_lgkm() {
    asm volatile("s_waitcnt lgkmcnt(0)" ::: "memory");
    __builtin_amdgcn_s_barrier();
    asm volatile("" ::: "memory");
}

__global__ __launch_bounds__(256, 1)
void exphydro_kernel(const float* __restrict__ g_snow, const float* __restrict__ g_water,
                     const float* __restrict__ g_pr, const float* __restrict__ g_tm,
                     const float* __restrict__ g_ld, const float* __restrict__ g_t,
                     const float* __restrict__ W1, const float* __restrict__ b1,
                     const float* __restrict__ W2, const float* __restrict__ b2,
                     const float* __restrict__ W3, const float* __restrict__ b3,
                     const float* __restrict__ W4, const float* __restrict__ b4,
                     float* __restrict__ out, int T)
{
    const int tid  = threadIdx.x;
    const int lane = tid & 63;
    const int wid  = tid >> 6;     // wave id 0..3, one SIMD each
    const int b    = blockIdx.x;   // one sample per block
    const int qk   = lane & 3;     // L2: K-subslice (rows [qk*16, qk*16+16))
    const int qo   = lane >> 2;    // L2: output index within this wave's slice
    const int col2 = 16 * wid + qo; // L2 output column this lane computes

    // forcing interleaved {pr, tm, ld, t} per timestep -- broadcast b128 reads
    __shared__ __align__(16) float4v s_f[TMAX];
    // per-wave private full h1 copy (in-wave DS order => no barrier)
    __shared__ __align__(16) float hc[4][64];
    // L3 partial exchange, double-buffered across consecutive rhs calls
    __shared__ __align__(16) float partAB[2][4][64];

    for (int i = tid; i < T; i += 256) {
        s_f[i] = float4v{g_pr[b * T + i], g_tm[b * T + i], g_ld[b * T + i], g_t[i]};
    }

    // --- weights ---
    // layer 1: all waves identical (per-lane column)
    float w1r[4];
#pragma unroll
    for (int j = 0; j < 4; ++j) w1r[j] = W1[j * 64 + lane];
    float b1v = b1[lane];
    // layer 2, N-split: lane computes output col2 over K-rows [qk*16, qk*16+16)
    float2v w2n[8];
#pragma unroll
    for (int k = 0; k < 8; ++k) {
        int r = qk * 16 + 2 * k;
        w2n[k] = float2v{W2[r * 64 + col2], W2[(r + 1) * 64 + col2]};
    }
    float b2s = b2[col2];
    // layer 3, K-split: wave owns rows [16*wid, 16*wid+16), lane = output col.
    // Scalar layout (consumed with SGPR-broadcast h2 via v_fmac).
    float w3f[16];
#pragma unroll
    for (int k = 0; k < 16; ++k) w3f[k] = W3[(16 * wid + k) * 64 + lane];
    float b3v = (wid == 0) ? b3[lane] : 0.0f;
    // layer 4: full, redundant per wave
    float w4r[5], b4r[5];
#pragma unroll
    for (int k = 0; k < 5; ++k) { w4r[k] = W4[lane * 5 + k]; b4r[k] = b4[k]; }

    __syncthreads();

    // full MLP from per-lane h1; o[0..4] VALID IN LANE 63 of every wave.
    // ONE (lgkm-only) barrier per call.
    auto mlp_o63 = [&](float h1, float (*part)[64], float* o) {
        // self-broadcast h1 within wave (h1 is identical in all waves)
        hc[wid][lane] = h1;
        const float* hq = &hc[wid][qk * 16];
        float4v q0 = *reinterpret_cast<const float4v*>(hq + 0);
        float4v q1 = *reinterpret_cast<const float4v*>(hq + 4);
        float4v q2 = *reinterpret_cast<const float4v*>(hq + 8);
        float4v q3 = *reinterpret_cast<const float4v*>(hq + 12);
        // L2 partial: 16-deep over this lane's K-subslice, output col2
        float2v a0 = float2v{0.0f, 0.0f}, a1 = float2v{0.0f, 0.0f};
        a0 = pk_fma(w2n[0], vlo(q0), a0); a1 = pk_fma(w2n[1], vhi(q0), a1);
        a0 = pk_fma(w2n[2], vlo(q1), a0); a1 = pk_fma(w2n[3], vhi(q1), a1);
        a0 = pk_fma(w2n[4], vlo(q2), a0); a1 = pk_fma(w2n[5], vhi(q2), a1);
        a0 = pk_fma(w2n[6], vlo(q3), a0); a1 = pk_fma(w2n[7], vhi(q3), a1);
        float2v sa = a0 + a1;
        float t2 = quad_sum(sa.x + sa.y);           // full 64-deep dot in quad
        float h2 = ftanh(t2 + b2s);
        // L3: h2 consumption is WAVE-UNIFORM (this wave's 16 values, resident
        // quad-redundant in lanes 4j) -> 16 readlane->SGPR + 16 v_fmac.
        float c0 = b3v, c1 = 0.0f, c2 = 0.0f, c3 = 0.0f;
#pragma unroll
        for (int j = 0; j < 16; j += 4) {
            float s0 = rl(h2, 4 * j);
            float s1 = rl(h2, 4 * (j + 1));
            float s2 = rl(h2, 4 * (j + 2));
            float s3 = rl(h2, 4 * (j + 3));
            c0 = fmaf(w3f[j + 0], s0, c0);
            c1 = fmaf(w3f[j + 1], s1, c1);
            c2 = fmaf(w3f[j + 2], s2, c2);
            c3 = fmaf(w3f[j + 3], s3, c3);
        }
        part[wid][lane] = (c0 + c1) + (c2 + c3);
        barrier_lgkm();                              // the ONE barrier (lgkm-only)
        float h3 = ftanh((part[0][lane] + part[1][lane]) + (part[2][lane] + part[3][lane]));
        // L4: 5 DPP trees, redundant in every wave (no LDS, no barrier)
#pragma unroll
        for (int k = 0; k < 5; ++k) o[k] = wave_sum63(w4r[k] * h3) + b4r[k];
    };

    // rhs: d0,d1 wave-uniform via readlane(63); o4 valid in lane 63 only.
    auto rhs = [&](float base, float y0v, float y1v, float ld, float snt,
                   float (*part)[64], float& d0, float& d1, float& o4) {
        // state-only nonlinearities first: overlap with the matvecs
        float step0 = fstep(y0v);
        float st1   = fstep(y1v);
        float h1 = ftanh(fmaf(w1r[0], y0v, fmaf(w1r[1], y1v, base)));
        float o[5];
        mlp_o63(h1, part, o);
        // epilogue computed with lane-63 values (garbage in other lanes, unused)
        float psnow = fmaxf(0.0f, fsinh(o[0]) * snt);
        float prain = fmaxf(0.0f, fsinh(o[1]));
        float melt  = fmaxf(0.0f, step0 * fsinh(o[2]));
        float eq    = st1 * fmaf(fexp(o[3]), ld, fexp(o[4]));
        float d0l = psnow - melt;
        float d1l = (prain + melt) - eq;
        d0 = rl(d0l, 63);
        d1 = rl(d1l, 63);
        o4 = o[4];
    };

    // wave-uniform state, replicated per wave (identical arithmetic => identical)
    float y0v = g_snow[b * T];
    float y1v = g_water[b * T];

    for (int st = 0; st < T - 1; ++st) {
        float4v fc = s_f[st];
        float4v fn = s_f[st + 1];

        float dt = fn.w - fc.w, half = 0.5f * dt, c6 = dt * (1.0f / 6.0f);
        float prH = 0.5f * (fc.x + fn.x);
        float tmH = 0.5f * (fc.y + fn.y);
        float ldH = 0.5f * (fc.z + fn.z);
        float snA = fstep(-fc.y), snH = fstep(-tmH), snC = fstep(-fn.y);
        float baseA = fmaf(w1r[2], fc.x, fmaf(w1r[3], fc.y, b1v));
        float baseH = fmaf(w1r[2], prH,  fmaf(w1r[3], tmH,  b1v));
        float baseC = fmaf(w1r[2], fn.x, fmaf(w1r[3], fn.y, b1v));

        float k1a, k1b, k2a, k2b, k3a, k3b, k4a, k4b, o4a, o4x;
        rhs(baseA, y0v, y1v, fc.z, snA, partAB[0], k1a, k1b, o4a);
        // q_out[:, st] == o[4] of the k1 MLP eval (integer-time interp == raw series)
        if (tid == 63) out[b * T + st] = o4a;
        rhs(baseH, fmaf(half, k1a, y0v), fmaf(half, k1b, y1v), ldH, snH, partAB[1], k2a, k2b, o4x);
        rhs(baseH, fmaf(half, k2a, y0v), fmaf(half, k2b, y1v), ldH, snH, partAB[0], k3a, k3b, o4x);
        rhs(baseC, fmaf(dt, k3a, y0v),   fmaf(dt, k3b, y1v),   fn.z, snC, partAB[1], k4a, k4b, o4x);

        y0v = fmaf(c6, (k1a + k4a) + 2.0f * (k2a + k3a), y0v);
        y1v = fmaf(c6, (k1b + k4b) + 2.0f * (k2b + k3b), y1v);
    }

    // last readout at t = T-1 with raw series values and final state
    {
        float4v fL = s_f[T - 1];
        float base = fmaf(w1r[2], fL.x, fmaf(w1r[3], fL.y, b1v));
        float h1 = ftanh(fmaf(w1r[0], y0v, fmaf(w1r[1], y1v, base)));
        float o[5];
        mlp_o63(h1, partAB[0], o);
        if (tid == 63) out[b * T + (T - 1)] = o[4];
    }
}

extern "C" void kernel_launch(void* const* d_in, const int* in_sizes, int n_in,
                              void* d_out, int out_size, void* d_ws, size_t ws_size,
                              hipStream_t stream) {
    const float* g_snow  = (const float*)d_in[0];
    const float* g_water = (const float*)d_in[1];
    const float* g_pr    = (const float*)d_in[2];
    const float* g_tm    = (const float*)d_in[3];
    const float* g_ld    = (const float*)d_in[4];
    const float* g_t     = (const float*)d_in[5];
    const float* W1 = (const float*)d_in[6];
    const float* b1 = (const float*)d_in[7];
    const float* W2 = (const float*)d_in[8];
    const float* b2 = (const float*)d_in[9];
    const float* W3 = (const float*)d_in[10];
    const float* b3 = (const float*)d_in[11];
    const float* W4 = (const float*)d_in[12];
    const float* b4 = (const float*)d_in[13];

    const int T = in_sizes[5];
    const int B = in_sizes[0] / T;

    exphydro_kernel<<<dim3(B), dim3(256), 0, stream>>>(
        g_snow, g_water, g_pr, g_tm, g_ld, g_t,
        W1, b1, W2, b2, W3, b3, W4, b4,
        (float*)d_out, T);
}